// Round 1
// baseline (47.290 us; speedup 1.0000x reference)
//
#include <hip/hip_runtime.h>

#define N 64
#define LC 64
#define LD 32

__global__ void zero_out_kernel(float* out) { out[0] = 0.0f; }

__global__ __launch_bounds__(256) void loss_kernel(
    const float* __restrict__ cont_w,   // [N,N,LC]
    const float* __restrict__ disc_w,   // [N,N,LD]
    const float* __restrict__ gap_w,    // [N,N,LD]
    const int*   __restrict__ cont_gold,// [N,N] values 0..LC
    const int*   __restrict__ disc_gold,// [T]   values 0..LD
    const int*   __restrict__ cont_idx, // [T] row into (N*N, LD) disc table
    const int*   __restrict__ disc_idx, // [T] row into (N*N, LD) gap table
    float* __restrict__ out, int T)
{
    const int idx = blockIdx.x * blockDim.x + threadIdx.x;
    float acc = 0.0f;

    if (idx < N * N) {
        // ---- continuous part: one cell per thread, upper triangle only ----
        const int i = idx >> 6, j = idx & 63;
        if (i <= j) {
            const float4* p = reinterpret_cast<const float4*>(cont_w + idx * LC);
            // pass 1: max (implicit null column value 0)
            float m = 0.0f;
            #pragma unroll
            for (int q = 0; q < LC / 4; ++q) {
                float4 x = p[q];
                m = fmaxf(m, fmaxf(fmaxf(x.x, x.y), fmaxf(x.z, x.w)));
            }
            // pass 2 (L1-hot re-read): sum of exp + gold pick
            const int g = cont_gold[idx];          // 0..LC (LC == null col, value 0)
            float s = __expf(-m);                  // null column
            float goldv = 0.0f;
            #pragma unroll
            for (int q = 0; q < LC / 4; ++q) {
                float4 x = p[q];
                s += __expf(x.x - m) + __expf(x.y - m) + __expf(x.z - m) + __expf(x.w - m);
                goldv = (4 * q + 0 == g) ? x.x : goldv;
                goldv = (4 * q + 1 == g) ? x.y : goldv;
                goldv = (4 * q + 2 == g) ? x.z : goldv;
                goldv = (4 * q + 3 == g) ? x.w : goldv;
            }
            acc = m + __logf(s) - goldv;
        }
    } else {
        // ---- discontinuous part: one tuple per thread ----
        const int t = idx - N * N;
        if (t < T) {
            const int a = cont_idx[t];
            const int b = disc_idx[t];
            const int g = disc_gold[t];            // 0..LD (LD == null col, value 0)
            const float4* pa = reinterpret_cast<const float4*>(disc_w + a * LD);
            const float4* pb = reinterpret_cast<const float4*>(gap_w + b * LD);
            float v[LD];
            float m = 0.0f;                        // implicit null column
            #pragma unroll
            for (int q = 0; q < LD / 4; ++q) {
                float4 x = pa[q];
                float4 y = pb[q];
                v[4 * q + 0] = x.x + y.x;
                v[4 * q + 1] = x.y + y.y;
                v[4 * q + 2] = x.z + y.z;
                v[4 * q + 3] = x.w + y.w;
            }
            #pragma unroll
            for (int c = 0; c < LD; ++c) m = fmaxf(m, v[c]);
            float s = __expf(-m);                  // null column
            float goldv = 0.0f;
            #pragma unroll
            for (int c = 0; c < LD; ++c) {
                s += __expf(v[c] - m);
                goldv = (c == g) ? v[c] : goldv;
            }
            acc = m + __logf(s) - goldv;
        }
    }

    // ---- block reduction: wave shuffle, then LDS across 4 waves ----
    #pragma unroll
    for (int off = 32; off > 0; off >>= 1)
        acc += __shfl_down(acc, off, 64);

    __shared__ float ws[4];
    const int lane = threadIdx.x & 63;
    const int wid  = threadIdx.x >> 6;
    if (lane == 0) ws[wid] = acc;
    __syncthreads();
    if (threadIdx.x == 0) {
        atomicAdd(out, ws[0] + ws[1] + ws[2] + ws[3]);
    }
}

extern "C" void kernel_launch(void* const* d_in, const int* in_sizes, int n_in,
                              void* d_out, int out_size, void* d_ws, size_t ws_size,
                              hipStream_t stream) {
    const float* cont_w    = (const float*)d_in[0];
    const float* disc_w    = (const float*)d_in[1];
    const float* gap_w     = (const float*)d_in[2];
    const int*   cont_gold = (const int*)d_in[3];
    const int*   disc_gold = (const int*)d_in[4];
    const int*   cont_idx  = (const int*)d_in[5];
    const int*   disc_idx  = (const int*)d_in[6];
    float* out = (float*)d_out;
    const int T = in_sizes[4];

    zero_out_kernel<<<1, 1, 0, stream>>>(out);

    const int total  = N * N + T;
    const int blocks = (total + 255) / 256;
    loss_kernel<<<blocks, 256, 0, stream>>>(cont_w, disc_w, gap_w, cont_gold,
                                            disc_gold, cont_idx, disc_idx, out, T);
}